// Round 3
// baseline (310.908 us; speedup 1.0000x reference)
//
#include <hip/hip_runtime.h>
#include <math.h>

#define C 128
#define N 1024
#define EPS 1e-6f
#define TR 8          // rows per block (512 blocks = 2 blocks/CU)
#define XSTRIDE 12    // floats; keeps float4 alignment, breaks pow-2 banks

typedef float f4 __attribute__((ext_vector_type(4)));

__global__ __launch_bounds__(256) void rlsa_fused(
    const float* __restrict__ feat,
    const float* __restrict__ wq, const float* __restrict__ bq,
    const float* __restrict__ wk, const float* __restrict__ bk,
    const float* __restrict__ wv, const float* __restrict__ bv,
    float* __restrict__ out_rlsa, float* __restrict__ out_ri,
    float* __restrict__ out_si)
{
    __shared__ __attribute__((aligned(16))) float xs[C * XSTRIDE]; // 6 KB
    __shared__ __attribute__((aligned(16))) float ks[TR * C];      // 4 KB
    __shared__ __attribute__((aligned(16))) float vs[TR * C];      // 4 KB
    __shared__ float sred[4][4];

    const int t    = threadIdx.x;
    const int c    = t & 127;
    const int half = t >> 7;              // rows half*4 .. half*4+3
    const int row0 = blockIdx.x * TR;     // flat row = b*N + n
    const int b    = row0 >> 10;
    const int n0   = row0 & 1023;

    // ---- stage x tile: xs[j][nl] = feat[b][j][n0+nl], one float4 per thread
    {
        const float* fb = feat + (size_t)b * C * N;
        int j = t >> 1, q = t & 1;
        float4 v = *(const float4*)(fb + (size_t)j * N + n0 + q * 4);
        *(float4*)&xs[j * XSTRIDE + q * 4] = v;
    }
    __syncthreads();

    // ---- dot products: thread (c, half) accumulates 4 rows ----
    float aq[4] = {0,0,0,0}, ak[4] = {0,0,0,0}, av[4] = {0,0,0,0};
    const float4* wq4 = (const float4*)(wq + c * C);
    const float4* wk4 = (const float4*)(wk + c * C);
    const float4* wv4 = (const float4*)(wv + c * C);
    const int xoff = half * 4;

    #pragma unroll 8
    for (int j4 = 0; j4 < 32; ++j4) {
        float4 q4 = wq4[j4];
        float4 k4 = wk4[j4];
        float4 v4 = wv4[j4];
        #pragma unroll
        for (int u = 0; u < 4; ++u) {
            // wave-broadcast LDS read (address independent of lane)
            float4 xa = *(const float4*)&xs[(j4 * 4 + u) * XSTRIDE + xoff];
            float wqv = (u == 0) ? q4.x : (u == 1) ? q4.y : (u == 2) ? q4.z : q4.w;
            float wkv = (u == 0) ? k4.x : (u == 1) ? k4.y : (u == 2) ? k4.z : k4.w;
            float wvv = (u == 0) ? v4.x : (u == 1) ? v4.y : (u == 2) ? v4.z : v4.w;
            aq[0] += xa.x * wqv; aq[1] += xa.y * wqv; aq[2] += xa.z * wqv; aq[3] += xa.w * wqv;
            ak[0] += xa.x * wkv; ak[1] += xa.y * wkv; ak[2] += xa.z * wkv; ak[3] += xa.w * wkv;
            av[0] += xa.x * wvv; av[1] += xa.y * wvv; av[2] += xa.z * wvv; av[3] += xa.w * wvv;
        }
    }

    const float bqc = bq[c], bkc = bk[c], bvc = bv[c];
    float qf[4], kf[4], vf[4];
    #pragma unroll
    for (int i = 0; i < 4; ++i) {
        float q = aq[i] + bqc;
        float k = ak[i] + bkc;
        qf[i] = q > 0.f ? q + 1.f : expf(q);   // elu(x)+1
        kf[i] = k > 0.f ? k + 1.f : expf(k);
        vf[i] = av[i] + bvc;
        ks[(half * 4 + i) * C + c] = kf[i];
        vs[(half * 4 + i) * C + c] = vf[i];
    }

    // ---- per-row S = sum_c qf*kf: wave shuffle + 2-wave combine ----
    const int wave = t >> 6;
    const int lane = t & 63;
    #pragma unroll
    for (int i = 0; i < 4; ++i) {
        float p = qf[i] * kf[i];
        #pragma unroll
        for (int off = 32; off > 0; off >>= 1) p += __shfl_down(p, off, 64);
        if (lane == 0) sred[wave][i] = p;
    }
    __syncthreads();

    // ---- Si / RLSA (coalesced per wave) ----
    #pragma unroll
    for (int i = 0; i < 4; ++i) {
        float S = sred[half * 2][i] + sred[half * 2 + 1][i];
        float coef = S / (S + EPS);
        size_t ro = (size_t)(row0 + half * 4 + i) * C + c;
        out_si[ro]   = kf[i];
        out_rlsa[ro] = coef * vf[i];
    }

    // ---- Ri[rr][cc][m] = k[cc] * v[m]; nontemporal coalesced float4 stream
    // f4-index f = i*256 + t -> cc = f>>5 = i*8 + t/32 ; m-quad = t&31 (invariant)
    const int mq = t & 31;
    const int chi = t >> 5;
    #pragma unroll
    for (int rr = 0; rr < TR; ++rr) {
        f4* rbase = (f4*)(out_ri + (size_t)(row0 + rr) * C * C);
        const float* krow = ks + rr * C;
        f4 vv = ((const f4*)(vs + rr * C))[mq];
        #pragma unroll
        for (int i = 0; i < 16; ++i) {
            float kc = krow[i * 8 + chi];
            __builtin_nontemporal_store(kc * vv, rbase + i * 256 + t);
        }
    }
}

extern "C" void kernel_launch(void* const* d_in, const int* in_sizes, int n_in,
                              void* d_out, int out_size, void* d_ws, size_t ws_size,
                              hipStream_t stream) {
    const float* feat = (const float*)d_in[0];
    const float* wq   = (const float*)d_in[1];
    const float* bq   = (const float*)d_in[2];
    const float* wk   = (const float*)d_in[3];
    const float* bk   = (const float*)d_in[4];
    const float* wv   = (const float*)d_in[5];
    const float* bv   = (const float*)d_in[6];

    float* out  = (float*)d_out;
    float* rlsa = out;                                   // 4*1024*128
    float* ri   = out + (size_t)4 * 1024 * 128;          // 4*1024*128*128
    float* si   = ri  + (size_t)4 * 1024 * 128 * 128;    // 4*1024*128

    rlsa_fused<<<4096 / TR, 256, 0, stream>>>(feat, wq, bq, wk, bk, wv, bv,
                                              rlsa, ri, si);
}